// Round 5
// baseline (624.528 us; speedup 1.0000x reference)
//
#include <hip/hip_runtime.h>

// 2-layer GCN (PyG GCNConv semantics): deg from dst(+self-loop), sym rsqrt norm,
// transform -> pull-aggregate (CSR, no fp32 atomics), bias, relu between layers.
//
// d_in: 0=x [n,256] f32, 1=edge_index [2,E] int32, 2=W1 [256,128], 3=b1 [128],
//       4=W2 [128,64], 5=b2 [64].  d_out: [n,64] f32.

constexpr int BLK = 256;

__global__ void k_zero_int(int* __restrict__ p, int n) {
    int i = blockIdx.x * blockDim.x + threadIdx.x;
    if (i < n) p[i] = 0;
}

__global__ void k_count(const int* __restrict__ dst, int* __restrict__ cnt, int E) {
    int e = blockIdx.x * blockDim.x + threadIdx.x;
    if (e < E) atomicAdd(&cnt[dst[e]], 1);
}

// block-local exclusive scan; bsum[b] = block total
__global__ void k_scan1(const int* __restrict__ cnt, int* __restrict__ off,
                        int* __restrict__ bsum, int n) {
    __shared__ int s[BLK];
    int t = threadIdx.x;
    int gid = blockIdx.x * BLK + t;
    int v = (gid < n) ? cnt[gid] : 0;
    s[t] = v;
    __syncthreads();
    #pragma unroll
    for (int d = 1; d < BLK; d <<= 1) {
        int x = (t >= d) ? s[t - d] : 0;
        __syncthreads();
        s[t] += x;
        __syncthreads();
    }
    if (gid < n) off[gid] = s[t] - v;
    if (t == BLK - 1) bsum[blockIdx.x] = s[t];
}

// exclusive scan of block sums (nb <= 512)
__global__ void k_scan2(int* __restrict__ bsum, int nb) {
    __shared__ int s[512];
    int t = threadIdx.x;
    int v = (t < nb) ? bsum[t] : 0;
    s[t] = v;
    __syncthreads();
    #pragma unroll
    for (int d = 1; d < 512; d <<= 1) {
        int x = (t >= d) ? s[t - d] : 0;
        __syncthreads();
        s[t] += x;
        __syncthreads();
    }
    if (t < nb) bsum[t] = s[t] - v;
}

// finalize offsets, init cursors, dinv = rsqrt(indeg+1)
__global__ void k_scan3(const int* __restrict__ cnt, int* __restrict__ off,
                        const int* __restrict__ bsum, int* __restrict__ cur,
                        float* __restrict__ dinv, int n, int E) {
    int i = blockIdx.x * blockDim.x + threadIdx.x;
    if (i < n) {
        int o = off[i] + bsum[i / BLK];
        off[i] = o;
        cur[i] = o;
        dinv[i] = rsqrtf((float)(cnt[i] + 1));
    }
    if (i == 0) off[n] = E;
}

__global__ void k_fill(const int* __restrict__ src, const int* __restrict__ dst,
                       int* __restrict__ cur, int* __restrict__ srcs, int E) {
    int e = blockIdx.x * blockDim.x + threadIdx.x;
    if (e < E) {
        int d = dst[e];
        int p = atomicAdd(&cur[d], 1);
        srcs[p] = src[e];
    }
}

// fp32 tiled GEMM: C[M,N] = A[M,K] @ B[K,N].  threads = (BM/TM)*(N/TN) = 256.
template <int K, int N, int BM, int BK, int TM, int TN>
__global__ __launch_bounds__(256) void k_gemm(const float* __restrict__ A,
                                              const float* __restrict__ B,
                                              float* __restrict__ C, int M) {
    constexpr int BN = N;
    constexpr int NTX = BN / TN;
    __shared__ float As[BM][BK];
    __shared__ float Bs[BK][BN];
    const int t = threadIdx.x;
    const int tx = t % NTX;
    const int ty = t / NTX;
    const int row0 = blockIdx.x * BM;
    float acc[TM][TN] = {};
    for (int kc = 0; kc < K; kc += BK) {
        #pragma unroll
        for (int i = 0; i < BM * BK / (256 * 4); ++i) {
            int f = (t + i * 256) * 4;
            int r = f / BK, kq = f % BK;
            float4 v = make_float4(0.f, 0.f, 0.f, 0.f);
            if (row0 + r < M)
                v = *(const float4*)(A + (size_t)(row0 + r) * K + kc + kq);
            *(float4*)&As[r][kq] = v;
        }
        #pragma unroll
        for (int i = 0; i < BK * BN / (256 * 4); ++i) {
            int f = (t + i * 256) * 4;
            int r = f / BN, c = f % BN;
            *(float4*)&Bs[r][c] = *(const float4*)(B + (size_t)(kc + r) * N + c);
        }
        __syncthreads();
        #pragma unroll
        for (int kk = 0; kk < BK; ++kk) {
            float a[TM], b[TN];
            #pragma unroll
            for (int i = 0; i < TM; ++i) a[i] = As[ty * TM + i][kk];
            #pragma unroll
            for (int j = 0; j < TN; ++j) b[j] = Bs[kk][tx * TN + j];
            #pragma unroll
            for (int i = 0; i < TM; ++i)
                #pragma unroll
                for (int j = 0; j < TN; ++j)
                    acc[i][j] = fmaf(a[i], b[j], acc[i][j]);
        }
        __syncthreads();
    }
    #pragma unroll
    for (int i = 0; i < TM; ++i) {
        int r = row0 + ty * TM + i;
        if (r < M)
            *(float4*)(C + (size_t)r * N + tx * TN) = *(float4*)&acc[i][0];
    }
}

// pull aggregation: one wave per node.
// out[i] = act( sum_{e in CSR(i)} h[src]*dinv[s]*dinv[i] + h[i]*dinv[i]^2 + bias )
// (s,w) pairs staged in LDS per 64-edge chunk; inner loop reads them at a
// wave-uniform address (HW broadcast, conflict-free). Same-wave LDS ops are
// in-order, so no barrier — NOTE: __syncthreads() here would deadlock (waves
// in a block have different trip counts).
template <int C, bool RELU>
__global__ __launch_bounds__(256) void k_aggregate(
    const float* __restrict__ h, const int* __restrict__ off,
    const int* __restrict__ srcs, const float* __restrict__ dinv,
    const float* __restrict__ bias, float* __restrict__ out, int n) {
    __shared__ float2 stage[256];
    const int tid = threadIdx.x;
    const int lane = tid & 63;
    const int wbase = tid & ~63;
    int wid = (int)((blockIdx.x * (size_t)blockDim.x + tid) >> 6);
    if (wid >= n) return;
    const float di = dinv[wid];
    const int e0 = off[wid], e1 = off[wid + 1];
    if constexpr (C == 128) {
        const float2* hp = (const float2*)h;
        float2 acc = hp[(size_t)wid * 64 + lane];
        acc.x *= di * di;
        acc.y *= di * di;
        for (int e = e0; e < e1; e += 64) {
            int m = e1 - e;
            if (m > 64) m = 64;
            float2 pk = make_float2(0.f, 0.f);
            if (lane < m) {
                int s = srcs[e + lane];
                pk.x = __int_as_float(s);
                pk.y = dinv[s] * di;
            }
            stage[tid] = pk;
            #pragma unroll 4
            for (int j = 0; j < m; ++j) {
                float2 sw = stage[wbase + j];
                int sj = __float_as_int(sw.x);
                float wj = sw.y;
                float2 v = hp[(size_t)sj * 64 + lane];
                acc.x = fmaf(v.x, wj, acc.x);
                acc.y = fmaf(v.y, wj, acc.y);
            }
        }
        float2 bb = ((const float2*)bias)[lane];
        acc.x += bb.x;
        acc.y += bb.y;
        if (RELU) {
            acc.x = fmaxf(acc.x, 0.f);
            acc.y = fmaxf(acc.y, 0.f);
        }
        ((float2*)out)[(size_t)wid * 64 + lane] = acc;
    } else {
        float acc = h[(size_t)wid * C + lane] * di * di;
        for (int e = e0; e < e1; e += 64) {
            int m = e1 - e;
            if (m > 64) m = 64;
            float2 pk = make_float2(0.f, 0.f);
            if (lane < m) {
                int s = srcs[e + lane];
                pk.x = __int_as_float(s);
                pk.y = dinv[s] * di;
            }
            stage[tid] = pk;
            #pragma unroll 4
            for (int j = 0; j < m; ++j) {
                float2 sw = stage[wbase + j];
                int sj = __float_as_int(sw.x);
                float wj = sw.y;
                acc = fmaf(h[(size_t)sj * C + lane], wj, acc);
            }
        }
        acc += bias[lane];
        if (RELU) acc = fmaxf(acc, 0.f);
        out[(size_t)wid * C + lane] = acc;
    }
}

extern "C" void kernel_launch(void* const* d_in, const int* in_sizes, int n_in,
                              void* d_out, int out_size, void* d_ws, size_t ws_size,
                              hipStream_t stream) {
    const float* x  = (const float*)d_in[0];
    const int*   ei = (const int*)d_in[1];
    const float* W1 = (const float*)d_in[2];
    const float* b1 = (const float*)d_in[3];
    const float* W2 = (const float*)d_in[4];
    const float* b2 = (const float*)d_in[5];
    float* out = (float*)d_out;

    const int n = in_sizes[0] / 256;   // 100000
    const int E = in_sizes[1] / 2;     // 1600000
    const int* src = ei;
    const int* dst = ei + E;

    // workspace carve (256B aligned): ~110 MB total (h3 aliases h1)
    char* p = (char*)d_ws;
    auto alloc = [&](size_t bytes) {
        char* q = p;
        p += (bytes + 255) & ~(size_t)255;
        return q;
    };
    int*   cnt  = (int*)alloc((size_t)n * 4);
    int*   off  = (int*)alloc((size_t)(n + 1) * 4);
    int*   cur  = (int*)alloc((size_t)n * 4);
    int*   bsum = (int*)alloc(4096);
    float* dinv = (float*)alloc((size_t)n * 4);
    int*   srcs = (int*)alloc((size_t)E * 4);
    float* h1   = (float*)alloc((size_t)n * 128 * 4);
    float* h2   = (float*)alloc((size_t)n * 128 * 4);
    float* h3   = h1;  // h1 dead after agg-1; reuse for layer-2 transform

    const int nb = (n + BLK - 1) / BLK;

    k_zero_int<<<nb, BLK, 0, stream>>>(cnt, n);
    k_count<<<(E + BLK - 1) / BLK, BLK, 0, stream>>>(dst, cnt, E);
    k_scan1<<<nb, BLK, 0, stream>>>(cnt, off, bsum, n);
    k_scan2<<<1, 512, 0, stream>>>(bsum, nb);
    k_scan3<<<nb, BLK, 0, stream>>>(cnt, off, bsum, cur, dinv, n, E);
    k_fill<<<(E + BLK - 1) / BLK, BLK, 0, stream>>>(src, dst, cur, srcs, E);

    // layer 1: h1 = x@W1 ; h2 = relu(agg(h1) + b1)
    k_gemm<256, 128, 64, 32, 8, 4><<<(n + 63) / 64, 256, 0, stream>>>(x, W1, h1, n);
    k_aggregate<128, true><<<(n + 3) / 4, 256, 0, stream>>>(h1, off, srcs, dinv, b1, h2, n);

    // layer 2: h3 = h2@W2 ; out = agg(h3) + b2
    k_gemm<128, 64, 64, 32, 4, 4><<<(n + 63) / 64, 256, 0, stream>>>(h2, W2, h3, n);
    k_aggregate<64, false><<<(n + 3) / 4, 256, 0, stream>>>(h3, off, srcs, dinv, b2, out, n);
}

// Round 7
// 511.817 us; speedup vs baseline: 1.2202x; 1.2202x over previous
//
#include <hip/hip_runtime.h>

// 2-layer GCN (PyG GCNConv semantics): deg from dst(+self-loop), sym rsqrt norm,
// transform -> pull-aggregate (CSR), bias, relu between layers.
// CSR built via bucketed radix scatter to avoid random-4B write amplification
// (round 5 profile: old k_fill wrote 105 MB to HBM for a 6.4 MB array, 130 us).
//
// d_in: 0=x [n,256] f32, 1=edge_index [2,E] int32, 2=W1 [256,128], 3=b1 [128],
//       4=W2 [128,64], 5=b2 [64].  d_out: [n,64] f32.

constexpr int NB_SHIFT = 7;     // 128 nodes per bucket
constexpr int NB_MAX   = 1024;  // supports n <= 131072
constexpr int BCAP     = 4096;  // LDS srcs staging per bucket (avg fill 2048)
constexpr int BHIST    = 256;   // blocks for hist/scatter passes

// ---- pass 1: per-block bucket histogram. ghist[b*B + blk] ----
__global__ __launch_bounds__(256) void k_hist(const int* __restrict__ dst,
                                              int* __restrict__ ghist,
                                              int E, int NB, int epb) {
    __shared__ int h[NB_MAX];
    const int t = threadIdx.x;
    for (int b = t; b < NB; b += 256) h[b] = 0;
    __syncthreads();
    const int e0 = blockIdx.x * epb;
    const int e1 = min(E, e0 + epb);
    for (int e = e0 + t; e < e1; e += 256) atomicAdd(&h[dst[e] >> NB_SHIFT], 1);
    __syncthreads();
    for (int b = t; b < NB; b += 256) ghist[b * gridDim.x + blockIdx.x] = h[b];
}

// ---- scan level 1: 512-thread blocks, exclusive per block + block sums ----
template <int TPB>
__global__ void k_scanL1(const int* __restrict__ in, int* __restrict__ out,
                         int* __restrict__ bsum, int ntot) {
    __shared__ int s[TPB];
    const int t = threadIdx.x;
    const int g = blockIdx.x * TPB + t;
    int v = (g < ntot) ? in[g] : 0;
    s[t] = v;
    __syncthreads();
    #pragma unroll
    for (int d = 1; d < TPB; d <<= 1) {
        int x = (t >= d) ? s[t - d] : 0;
        __syncthreads();
        s[t] += x;
        __syncthreads();
    }
    if (g < ntot) out[g] = s[t] - v;
    if (t == TPB - 1) bsum[blockIdx.x] = s[t];
}

// ---- scan level 2: exclusive scan of <=512 block sums ----
__global__ void k_scanL2(int* __restrict__ bsum, int nb) {
    __shared__ int s[512];
    const int t = threadIdx.x;
    int v = (t < nb) ? bsum[t] : 0;
    s[t] = v;
    __syncthreads();
    #pragma unroll
    for (int d = 1; d < 512; d <<= 1) {
        int x = (t >= d) ? s[t - d] : 0;
        __syncthreads();
        s[t] += x;
        __syncthreads();
    }
    if (t < nb) bsum[t] = s[t] - v;
}

// ---- pass 2: scatter (src,dst) into bucket-grouped pairs; each block writes
//      its pre-reserved contiguous segment per bucket (sequential-ish writes) ----
__global__ __launch_bounds__(256) void k_scatter(const int* __restrict__ src,
                                                 const int* __restrict__ dst,
                                                 const int* __restrict__ scan,
                                                 const int* __restrict__ bsum,
                                                 int2* __restrict__ pairs,
                                                 int E, int NB, int epb) {
    __shared__ int cur[NB_MAX];
    const int t = threadIdx.x;
    const int B = gridDim.x;
    const int blk = blockIdx.x;
    for (int b = t; b < NB; b += 256) {
        int idx = b * B + blk;
        cur[b] = scan[idx] + bsum[idx >> 9];
    }
    __syncthreads();
    const int e0 = blk * epb;
    const int e1 = min(E, e0 + epb);
    for (int e = e0 + t; e < e1; e += 256) {
        int d = dst[e];
        int slot = atomicAdd(&cur[d >> NB_SHIFT], 1);
        pairs[slot] = make_int2(src[e], d);
    }
}

// ---- pass 3: one block per bucket. Local CSR in LDS, coalesced srcs
//      write-out; emits off[] and dinv[] for this bucket's nodes. ----
__global__ __launch_bounds__(256) void k_build(const int2* __restrict__ pairs,
                                               const int* __restrict__ scan,
                                               const int* __restrict__ bsum,
                                               int* __restrict__ srcs,
                                               int* __restrict__ off,
                                               float* __restrict__ dinv,
                                               int n, int E, int NB, int B) {
    __shared__ int h[128], loff[128], curs[128];
    __shared__ int sb[BCAP];
    const int t = threadIdx.x;
    const int bk = blockIdx.x;
    const int i0 = bk * B;
    const int base = scan[i0] + bsum[i0 >> 9];
    const int nextbase = (bk + 1 < NB) ? (scan[i0 + B] + bsum[(i0 + B) >> 9]) : E;
    const int count = nextbase - base;
    if (t < 128) h[t] = 0;
    __syncthreads();
    for (int e = t; e < count; e += 256) atomicAdd(&h[pairs[base + e].y & 127], 1);
    __syncthreads();
    if (t < 128) loff[t] = h[t];
    __syncthreads();
    #pragma unroll
    for (int d = 1; d < 128; d <<= 1) {
        int x = 0;
        if (t < 128 && t >= d) x = loff[t - d];
        __syncthreads();
        if (t < 128) loff[t] += x;
        __syncthreads();
    }
    if (t < 128) curs[t] = loff[t] - h[t];  // exclusive
    __syncthreads();
    for (int e = t; e < count; e += 256) {
        int2 p = pairs[base + e];
        int slot = atomicAdd(&curs[p.y & 127], 1);
        if (slot < BCAP) sb[slot] = p.x;
        else srcs[base + slot] = p.x;  // overflow fallback (statistically unreachable)
    }
    __syncthreads();
    const int lim = min(count, BCAP);
    for (int e = t; e < lim; e += 256) srcs[base + e] = sb[e];
    const int node0 = bk << NB_SHIFT;
    if (t < 128) {
        int node = node0 + t;
        if (node < n) {
            off[node] = base + (loff[t] - h[t]);
            dinv[node] = rsqrtf((float)(h[t] + 1));
        }
    }
    if (bk == 0 && t == 0) off[n] = E;
}

// fp32 tiled GEMM: C[M,N] = A[M,K] @ B[K,N].  threads = (BM/TM)*(N/TN) = 256.
template <int K, int N, int BM, int BK, int TM, int TN>
__global__ __launch_bounds__(256) void k_gemm(const float* __restrict__ A,
                                              const float* __restrict__ B,
                                              float* __restrict__ C, int M) {
    constexpr int BN = N;
    constexpr int NTX = BN / TN;
    __shared__ float As[BM][BK];
    __shared__ float Bs[BK][BN];
    const int t = threadIdx.x;
    const int tx = t % NTX;
    const int ty = t / NTX;
    const int row0 = blockIdx.x * BM;
    float acc[TM][TN] = {};
    for (int kc = 0; kc < K; kc += BK) {
        #pragma unroll
        for (int i = 0; i < BM * BK / (256 * 4); ++i) {
            int f = (t + i * 256) * 4;
            int r = f / BK, kq = f % BK;
            float4 v = make_float4(0.f, 0.f, 0.f, 0.f);
            if (row0 + r < M)
                v = *(const float4*)(A + (size_t)(row0 + r) * K + kc + kq);
            *(float4*)&As[r][kq] = v;
        }
        #pragma unroll
        for (int i = 0; i < BK * BN / (256 * 4); ++i) {
            int f = (t + i * 256) * 4;
            int r = f / BN, c = f % BN;
            *(float4*)&Bs[r][c] = *(const float4*)(B + (size_t)(kc + r) * N + c);
        }
        __syncthreads();
        #pragma unroll
        for (int kk = 0; kk < BK; ++kk) {
            float a[TM], b[TN];
            #pragma unroll
            for (int i = 0; i < TM; ++i) a[i] = As[ty * TM + i][kk];
            #pragma unroll
            for (int j = 0; j < TN; ++j) b[j] = Bs[kk][tx * TN + j];
            #pragma unroll
            for (int i = 0; i < TM; ++i)
                #pragma unroll
                for (int j = 0; j < TN; ++j)
                    acc[i][j] = fmaf(a[i], b[j], acc[i][j]);
        }
        __syncthreads();
    }
    #pragma unroll
    for (int i = 0; i < TM; ++i) {
        int r = row0 + ty * TM + i;
        if (r < M)
            *(float4*)(C + (size_t)r * N + tx * TN) = *(float4*)&acc[i][0];
    }
}

// pull aggregation: one wave per node.
// out[i] = act( sum_{e in CSR(i)} h[src]*dinv[s]*dinv[i] + h[i]*dinv[i]^2 + bias )
// (s,w) pairs staged in LDS per 64-edge chunk at a wave-uniform read address.
// Same-wave LDS ops are in-order; NO barrier (waves have different trip counts).
template <int C, bool RELU>
__global__ __launch_bounds__(256) void k_aggregate(
    const float* __restrict__ h, const int* __restrict__ off,
    const int* __restrict__ srcs, const float* __restrict__ dinv,
    const float* __restrict__ bias, float* __restrict__ out, int n) {
    __shared__ float2 stage[256];
    const int tid = threadIdx.x;
    const int lane = tid & 63;
    const int wbase = tid & ~63;
    int wid = (int)((blockIdx.x * (size_t)blockDim.x + tid) >> 6);
    if (wid >= n) return;
    const float di = dinv[wid];
    const int e0 = off[wid], e1 = off[wid + 1];
    if constexpr (C == 128) {
        const float2* hp = (const float2*)h;
        float2 acc = hp[(size_t)wid * 64 + lane];
        acc.x *= di * di;
        acc.y *= di * di;
        for (int e = e0; e < e1; e += 64) {
            int m = e1 - e;
            if (m > 64) m = 64;
            float2 pk = make_float2(0.f, 0.f);
            if (lane < m) {
                int s = srcs[e + lane];
                pk.x = __int_as_float(s);
                pk.y = dinv[s] * di;
            }
            stage[tid] = pk;
            #pragma unroll 4
            for (int j = 0; j < m; ++j) {
                float2 sw = stage[wbase + j];
                int sj = __float_as_int(sw.x);
                float wj = sw.y;
                float2 v = hp[(size_t)sj * 64 + lane];
                acc.x = fmaf(v.x, wj, acc.x);
                acc.y = fmaf(v.y, wj, acc.y);
            }
        }
        float2 bb = ((const float2*)bias)[lane];
        acc.x += bb.x;
        acc.y += bb.y;
        if (RELU) {
            acc.x = fmaxf(acc.x, 0.f);
            acc.y = fmaxf(acc.y, 0.f);
        }
        ((float2*)out)[(size_t)wid * 64 + lane] = acc;
    } else {
        float acc = h[(size_t)wid * C + lane] * di * di;
        for (int e = e0; e < e1; e += 64) {
            int m = e1 - e;
            if (m > 64) m = 64;
            float2 pk = make_float2(0.f, 0.f);
            if (lane < m) {
                int s = srcs[e + lane];
                pk.x = __int_as_float(s);
                pk.y = dinv[s] * di;
            }
            stage[tid] = pk;
            #pragma unroll 4
            for (int j = 0; j < m; ++j) {
                float2 sw = stage[wbase + j];
                int sj = __float_as_int(sw.x);
                float wj = sw.y;
                acc = fmaf(h[(size_t)sj * C + lane], wj, acc);
            }
        }
        acc += bias[lane];
        if (RELU) acc = fmaxf(acc, 0.f);
        out[(size_t)wid * C + lane] = acc;
    }
}

extern "C" void kernel_launch(void* const* d_in, const int* in_sizes, int n_in,
                              void* d_out, int out_size, void* d_ws, size_t ws_size,
                              hipStream_t stream) {
    const float* x  = (const float*)d_in[0];
    const int*   ei = (const int*)d_in[1];
    const float* W1 = (const float*)d_in[2];
    const float* b1 = (const float*)d_in[3];
    const float* W2 = (const float*)d_in[4];
    const float* b2 = (const float*)d_in[5];
    float* out = (float*)d_out;

    const int n = in_sizes[0] / 256;   // 100000
    const int E = in_sizes[1] / 2;     // 1600000
    const int* src = ei;
    const int* dst = ei + E;

    const int NB  = (n + 127) >> NB_SHIFT;           // 782 buckets
    const int B   = BHIST;                           // 256 hist/scatter blocks
    const int epb = (E + B - 1) / B;                 // edges per block
    const int ntot = NB * B;                         // scan length (200192)
    const int gL1 = (ntot + 511) / 512;              // 391 <= 512

    // workspace carve (256B aligned), ~110 MB. pairs aliases h1 (dead before gemm1).
    char* p = (char*)d_ws;
    auto alloc = [&](size_t bytes) {
        char* q = p;
        p += (bytes + 255) & ~(size_t)255;
        return q;
    };
    int*   ghist = (int*)alloc((size_t)ntot * 4);
    int*   scan  = (int*)alloc((size_t)ntot * 4);
    int*   bsum  = (int*)alloc(2048);
    int*   off   = (int*)alloc((size_t)(n + 1) * 4);
    float* dinv  = (float*)alloc((size_t)n * 4);
    int*   srcs  = (int*)alloc((size_t)E * 4);
    float* h1    = (float*)alloc((size_t)n * 128 * 4);
    float* h2    = (float*)alloc((size_t)n * 128 * 4);
    int2*  pairs = (int2*)h1;   // E*8 = 12.8 MB <= h1's 51.2 MB; dead before gemm1
    float* h3    = h1;          // h1 dead after agg-1; reuse for layer-2 transform

    // CSR build
    k_hist<<<B, 256, 0, stream>>>(dst, ghist, E, NB, epb);
    k_scanL1<512><<<gL1, 512, 0, stream>>>(ghist, scan, bsum, ntot);
    k_scanL2<<<1, 512, 0, stream>>>(bsum, gL1);
    k_scatter<<<B, 256, 0, stream>>>(src, dst, scan, bsum, pairs, E, NB, epb);
    k_build<<<NB, 256, 0, stream>>>(pairs, scan, bsum, srcs, off, dinv, n, E, NB, B);

    // layer 1: h1 = x@W1 ; h2 = relu(agg(h1) + b1)
    k_gemm<256, 128, 64, 32, 8, 4><<<(n + 63) / 64, 256, 0, stream>>>(x, W1, h1, n);
    k_aggregate<128, true><<<(n + 3) / 4, 256, 0, stream>>>(h1, off, srcs, dinv, b1, h2, n);

    // layer 2: h3 = h2@W2 ; out = agg(h3) + b2
    k_gemm<128, 64, 64, 32, 4, 4><<<(n + 63) / 64, 256, 0, stream>>>(h2, W2, h3, n);
    k_aggregate<64, false><<<(n + 3) / 4, 256, 0, stream>>>(h3, off, srcs, dinv, b2, out, n);
}

// Round 8
// 503.446 us; speedup vs baseline: 1.2405x; 1.0166x over previous
//
#include <hip/hip_runtime.h>

// 2-layer GCN (PyG GCNConv semantics): deg from dst(+self-loop), sym rsqrt norm,
// transform -> pull-aggregate (CSR), bias, relu between layers.
// CSR via bucketed radix scatter (r5: k_fill wrote 105MB amplified for 6.4MB).
// r7: GEMM2 fused into agg1 epilogue (agg is linear; LDS pipe idle during
// gather phase -> W2 matmul hides under VMEM shadow). h2 round-trip deleted.
//
// d_in: 0=x [n,256] f32, 1=edge_index [2,E] int32, 2=W1 [256,128], 3=b1 [128],
//       4=W2 [128,64], 5=b2 [64].  d_out: [n,64] f32.

constexpr int NB_SHIFT = 7;     // 128 nodes per bucket
constexpr int NB_MAX   = 1024;  // supports n <= 131072
constexpr int BCAP     = 4096;  // LDS srcs staging per bucket (avg fill 2048)
constexpr int BHIST    = 256;   // blocks for hist/scatter passes

// ---- pass 1: per-block bucket histogram. ghist[b*B + blk] ----
__global__ __launch_bounds__(256) void k_hist(const int* __restrict__ dst,
                                              int* __restrict__ ghist,
                                              int E, int NB, int epb) {
    __shared__ int h[NB_MAX];
    const int t = threadIdx.x;
    for (int b = t; b < NB; b += 256) h[b] = 0;
    __syncthreads();
    const int e0 = blockIdx.x * epb;
    const int e1 = min(E, e0 + epb);
    for (int e = e0 + t; e < e1; e += 256) atomicAdd(&h[dst[e] >> NB_SHIFT], 1);
    __syncthreads();
    for (int b = t; b < NB; b += 256) ghist[b * gridDim.x + blockIdx.x] = h[b];
}

// ---- scan level 1: 512-thread blocks, exclusive per block + block sums ----
template <int TPB>
__global__ void k_scanL1(const int* __restrict__ in, int* __restrict__ out,
                         int* __restrict__ bsum, int ntot) {
    __shared__ int s[TPB];
    const int t = threadIdx.x;
    const int g = blockIdx.x * TPB + t;
    int v = (g < ntot) ? in[g] : 0;
    s[t] = v;
    __syncthreads();
    #pragma unroll
    for (int d = 1; d < TPB; d <<= 1) {
        int x = (t >= d) ? s[t - d] : 0;
        __syncthreads();
        s[t] += x;
        __syncthreads();
    }
    if (g < ntot) out[g] = s[t] - v;
    if (t == TPB - 1) bsum[blockIdx.x] = s[t];
}

// ---- scan level 2: exclusive scan of <=512 block sums ----
__global__ void k_scanL2(int* __restrict__ bsum, int nb) {
    __shared__ int s[512];
    const int t = threadIdx.x;
    int v = (t < nb) ? bsum[t] : 0;
    s[t] = v;
    __syncthreads();
    #pragma unroll
    for (int d = 1; d < 512; d <<= 1) {
        int x = (t >= d) ? s[t - d] : 0;
        __syncthreads();
        s[t] += x;
        __syncthreads();
    }
    if (t < nb) bsum[t] = s[t] - v;
}

// ---- pass 2: scatter (src,dst) into bucket-grouped pairs ----
__global__ __launch_bounds__(256) void k_scatter(const int* __restrict__ src,
                                                 const int* __restrict__ dst,
                                                 const int* __restrict__ scan,
                                                 const int* __restrict__ bsum,
                                                 int2* __restrict__ pairs,
                                                 int E, int NB, int epb) {
    __shared__ int cur[NB_MAX];
    const int t = threadIdx.x;
    const int B = gridDim.x;
    const int blk = blockIdx.x;
    for (int b = t; b < NB; b += 256) {
        int idx = b * B + blk;
        cur[b] = scan[idx] + bsum[idx >> 9];
    }
    __syncthreads();
    const int e0 = blk * epb;
    const int e1 = min(E, e0 + epb);
    for (int e = e0 + t; e < e1; e += 256) {
        int d = dst[e];
        int slot = atomicAdd(&cur[d >> NB_SHIFT], 1);
        pairs[slot] = make_int2(src[e], d);
    }
}

// ---- pass 3: one block per bucket; local CSR in LDS, coalesced srcs out ----
__global__ __launch_bounds__(256) void k_build(const int2* __restrict__ pairs,
                                               const int* __restrict__ scan,
                                               const int* __restrict__ bsum,
                                               int* __restrict__ srcs,
                                               int* __restrict__ off,
                                               float* __restrict__ dinv,
                                               int n, int E, int NB, int B) {
    __shared__ int h[128], loff[128], curs[128];
    __shared__ int sb[BCAP];
    const int t = threadIdx.x;
    const int bk = blockIdx.x;
    const int i0 = bk * B;
    const int base = scan[i0] + bsum[i0 >> 9];
    const int nextbase = (bk + 1 < NB) ? (scan[i0 + B] + bsum[(i0 + B) >> 9]) : E;
    const int count = nextbase - base;
    if (t < 128) h[t] = 0;
    __syncthreads();
    for (int e = t; e < count; e += 256) atomicAdd(&h[pairs[base + e].y & 127], 1);
    __syncthreads();
    if (t < 128) loff[t] = h[t];
    __syncthreads();
    #pragma unroll
    for (int d = 1; d < 128; d <<= 1) {
        int x = 0;
        if (t < 128 && t >= d) x = loff[t - d];
        __syncthreads();
        if (t < 128) loff[t] += x;
        __syncthreads();
    }
    if (t < 128) curs[t] = loff[t] - h[t];  // exclusive
    __syncthreads();
    for (int e = t; e < count; e += 256) {
        int2 p = pairs[base + e];
        int slot = atomicAdd(&curs[p.y & 127], 1);
        if (slot < BCAP) sb[slot] = p.x;
        else srcs[base + slot] = p.x;  // overflow fallback (statistically unreachable)
    }
    __syncthreads();
    const int lim = min(count, BCAP);
    for (int e = t; e < lim; e += 256) srcs[base + e] = sb[e];
    const int node0 = bk << NB_SHIFT;
    if (t < 128) {
        int node = node0 + t;
        if (node < n) {
            off[node] = base + (loff[t] - h[t]);
            dinv[node] = rsqrtf((float)(h[t] + 1));
        }
    }
    if (bk == 0 && t == 0) off[n] = E;
}

// fp32 tiled GEMM: C[M,N] = A[M,K] @ B[K,N].  threads = (BM/TM)*(N/TN) = 256.
template <int K, int N, int BM, int BK, int TM, int TN>
__global__ __launch_bounds__(256) void k_gemm(const float* __restrict__ A,
                                              const float* __restrict__ B,
                                              float* __restrict__ C, int M) {
    constexpr int BN = N;
    constexpr int NTX = BN / TN;
    __shared__ float As[BM][BK];
    __shared__ float Bs[BK][BN];
    const int t = threadIdx.x;
    const int tx = t % NTX;
    const int ty = t / NTX;
    const int row0 = blockIdx.x * BM;
    float acc[TM][TN] = {};
    for (int kc = 0; kc < K; kc += BK) {
        #pragma unroll
        for (int i = 0; i < BM * BK / (256 * 4); ++i) {
            int f = (t + i * 256) * 4;
            int r = f / BK, kq = f % BK;
            float4 v = make_float4(0.f, 0.f, 0.f, 0.f);
            if (row0 + r < M)
                v = *(const float4*)(A + (size_t)(row0 + r) * K + kc + kq);
            *(float4*)&As[r][kq] = v;
        }
        #pragma unroll
        for (int i = 0; i < BK * BN / (256 * 4); ++i) {
            int f = (t + i * 256) * 4;
            int r = f / BN, c = f % BN;
            *(float4*)&Bs[r][c] = *(const float4*)(B + (size_t)(kc + r) * N + c);
        }
        __syncthreads();
        #pragma unroll
        for (int kk = 0; kk < BK; ++kk) {
            float a[TM], b[TN];
            #pragma unroll
            for (int i = 0; i < TM; ++i) a[i] = As[ty * TM + i][kk];
            #pragma unroll
            for (int j = 0; j < TN; ++j) b[j] = Bs[kk][tx * TN + j];
            #pragma unroll
            for (int i = 0; i < TM; ++i)
                #pragma unroll
                for (int j = 0; j < TN; ++j)
                    acc[i][j] = fmaf(a[i], b[j], acc[i][j]);
        }
        __syncthreads();
    }
    #pragma unroll
    for (int i = 0; i < TM; ++i) {
        int r = row0 + ty * TM + i;
        if (r < M)
            *(float4*)(C + (size_t)r * N + tx * TN) = *(float4*)&acc[i][0];
    }
}

// ---- FUSED agg1 + GEMM2: one wave per node (8 nodes / 512-thr block).
// row = relu(agg(h1) + b1)  (in regs, float2/lane)
// h3[node][c] = sum_k row[k] * W2[k][c]   (row stashed in wave's LDS slot;
// W2 staged in LDS 32KB; lane c computes one output channel)
// stage slots double as the row buffer after the gather loop (same-wave
// in-order LDS, no barrier; the only __syncthreads is pre-divergence).
__global__ __launch_bounds__(512) void k_agg_mm(
    const float* __restrict__ h, const int* __restrict__ off,
    const int* __restrict__ srcs, const float* __restrict__ dinv,
    const float* __restrict__ b1, const float* __restrict__ W2,
    float* __restrict__ h3, int n) {
    __shared__ float W2s[128 * 64];
    __shared__ float2 stage[512];
    const int tid = threadIdx.x;
    // cooperative W2 stage: 8192 floats = 512 thr x 4 float4
    #pragma unroll
    for (int i = 0; i < 4; ++i) {
        int f = (tid + i * 512) * 4;
        *(float4*)&W2s[f] = *(const float4*)&W2[f];
    }
    __syncthreads();  // only barrier; before any divergence
    const int lane = tid & 63;
    const int wbase = tid & ~63;
    const int wid = blockIdx.x * 8 + (tid >> 6);
    if (wid >= n) return;
    const float di = dinv[wid];
    const int e0 = off[wid], e1 = off[wid + 1];
    const float2* hp = (const float2*)h;
    float2 acc = hp[(size_t)wid * 64 + lane];
    acc.x *= di * di;
    acc.y *= di * di;
    for (int e = e0; e < e1; e += 64) {
        int m = e1 - e;
        if (m > 64) m = 64;
        float2 pk = make_float2(0.f, 0.f);
        if (lane < m) {
            int s = srcs[e + lane];
            pk.x = __int_as_float(s);
            pk.y = dinv[s] * di;
        }
        stage[tid] = pk;
        #pragma unroll 4
        for (int j = 0; j < m; ++j) {
            float2 sw = stage[wbase + j];
            int sj = __float_as_int(sw.x);
            float wj = sw.y;
            float2 v = hp[(size_t)sj * 64 + lane];
            acc.x = fmaf(v.x, wj, acc.x);
            acc.y = fmaf(v.y, wj, acc.y);
        }
    }
    // bias + relu -> h2 row; stash in this wave's stage region
    float2 bb = ((const float2*)b1)[lane];
    acc.x = fmaxf(acc.x + bb.x, 0.f);
    acc.y = fmaxf(acc.y + bb.y, 0.f);
    stage[tid] = acc;  // flat: row[2*lane], row[2*lane+1]
    const float* row = (const float*)&stage[wbase];
    // h3 row: lane computes channel c = lane. row[k]: wave-uniform broadcast;
    // W2s[k*64+lane]: stride-1 across lanes (2 lanes/bank, free).
    float s0 = 0.f, s1 = 0.f, s2 = 0.f, s3 = 0.f;
    #pragma unroll 8
    for (int k = 0; k < 128; k += 4) {
        s0 = fmaf(row[k + 0], W2s[(k + 0) * 64 + lane], s0);
        s1 = fmaf(row[k + 1], W2s[(k + 1) * 64 + lane], s1);
        s2 = fmaf(row[k + 2], W2s[(k + 2) * 64 + lane], s2);
        s3 = fmaf(row[k + 3], W2s[(k + 3) * 64 + lane], s3);
    }
    h3[(size_t)wid * 64 + lane] = (s0 + s1) + (s2 + s3);
}

// pull aggregation (64-wide): one wave per node. out = agg(h3) + b2 (no relu).
template <int C, bool RELU>
__global__ __launch_bounds__(256) void k_aggregate(
    const float* __restrict__ h, const int* __restrict__ off,
    const int* __restrict__ srcs, const float* __restrict__ dinv,
    const float* __restrict__ bias, float* __restrict__ out, int n) {
    __shared__ float2 stage[256];
    const int tid = threadIdx.x;
    const int lane = tid & 63;
    const int wbase = tid & ~63;
    int wid = (int)((blockIdx.x * (size_t)blockDim.x + tid) >> 6);
    if (wid >= n) return;
    const float di = dinv[wid];
    const int e0 = off[wid], e1 = off[wid + 1];
    float acc = h[(size_t)wid * C + lane] * di * di;
    for (int e = e0; e < e1; e += 64) {
        int m = e1 - e;
        if (m > 64) m = 64;
        float2 pk = make_float2(0.f, 0.f);
        if (lane < m) {
            int s = srcs[e + lane];
            pk.x = __int_as_float(s);
            pk.y = dinv[s] * di;
        }
        stage[tid] = pk;
        #pragma unroll 4
        for (int j = 0; j < m; ++j) {
            float2 sw = stage[wbase + j];
            int sj = __float_as_int(sw.x);
            float wj = sw.y;
            acc = fmaf(h[(size_t)sj * C + lane], wj, acc);
        }
    }
    acc += bias[lane];
    if (RELU) acc = fmaxf(acc, 0.f);
    out[(size_t)wid * C + lane] = acc;
}

extern "C" void kernel_launch(void* const* d_in, const int* in_sizes, int n_in,
                              void* d_out, int out_size, void* d_ws, size_t ws_size,
                              hipStream_t stream) {
    const float* x  = (const float*)d_in[0];
    const int*   ei = (const int*)d_in[1];
    const float* W1 = (const float*)d_in[2];
    const float* b1 = (const float*)d_in[3];
    const float* W2 = (const float*)d_in[4];
    const float* b2 = (const float*)d_in[5];
    float* out = (float*)d_out;

    const int n = in_sizes[0] / 256;   // 100000
    const int E = in_sizes[1] / 2;     // 1600000
    const int* src = ei;
    const int* dst = ei + E;

    const int NB  = (n + 127) >> NB_SHIFT;           // 782 buckets
    const int B   = BHIST;                           // 256 hist/scatter blocks
    const int epb = (E + B - 1) / B;                 // edges per block
    const int ntot = NB * B;                         // scan length (200192)
    const int gL1 = (ntot + 511) / 512;              // 391 <= 512

    // workspace carve (256B aligned), ~86 MB. pairs aliases h1 (dead before gemm1).
    char* p = (char*)d_ws;
    auto alloc = [&](size_t bytes) {
        char* q = p;
        p += (bytes + 255) & ~(size_t)255;
        return q;
    };
    int*   ghist = (int*)alloc((size_t)ntot * 4);
    int*   scan  = (int*)alloc((size_t)ntot * 4);
    int*   bsum  = (int*)alloc(2048);
    int*   off   = (int*)alloc((size_t)(n + 1) * 4);
    float* dinv  = (float*)alloc((size_t)n * 4);
    int*   srcs  = (int*)alloc((size_t)E * 4);
    float* h1    = (float*)alloc((size_t)n * 128 * 4);
    float* h3    = (float*)alloc((size_t)n * 64 * 4);
    int2*  pairs = (int2*)h1;   // E*8 = 12.8 MB <= h1's 51.2 MB; dead before gemm1

    // CSR build
    k_hist<<<B, 256, 0, stream>>>(dst, ghist, E, NB, epb);
    k_scanL1<512><<<gL1, 512, 0, stream>>>(ghist, scan, bsum, ntot);
    k_scanL2<<<1, 512, 0, stream>>>(bsum, gL1);
    k_scatter<<<B, 256, 0, stream>>>(src, dst, scan, bsum, pairs, E, NB, epb);
    k_build<<<NB, 256, 0, stream>>>(pairs, scan, bsum, srcs, off, dinv, n, E, NB, B);

    // layer 1 transform: h1 = x@W1
    k_gemm<256, 128, 64, 32, 8, 4><<<(n + 63) / 64, 256, 0, stream>>>(x, W1, h1, n);
    // fused: h3 = relu(agg(h1)+b1) @ W2
    k_agg_mm<<<(n + 7) / 8, 512, 0, stream>>>(h1, off, srcs, dinv, b1, W2, h3, n);
    // layer 2 aggregate: out = agg(h3) + b2
    k_aggregate<64, false><<<(n + 3) / 4, 256, 0, stream>>>(h3, off, srcs, dinv, b2, out, n);
}

// Round 9
// 473.320 us; speedup vs baseline: 1.3195x; 1.0636x over previous
//
#include <hip/hip_runtime.h>

// 2-layer GCN (PyG GCNConv semantics). CSR via bucketed radix scatter (r5).
// r7: GEMM2 fused into agg1 epilogue. r8 post-mortem: fusion cost occupancy
// (512-thr tails); gather is BW-bound on L2-miss path (414 MB @ 3 TB/s).
// r9: gathered tensors h1/h3 + LDS W2 stored as bf16 (storage only; all
// accumulation fp32) -> halves gather bytes; 256-thr fused blocks restore
// occupancy (18.25 KB LDS -> 8 blocks/CU).
//
// d_in: 0=x [n,256] f32, 1=edge_index [2,E] int32, 2=W1 [256,128], 3=b1 [128],
//       4=W2 [128,64], 5=b2 [64].  d_out: [n,64] f32.

constexpr int NB_SHIFT = 7;     // 128 nodes per bucket
constexpr int NB_MAX   = 1024;  // supports n <= 131072
constexpr int BCAP     = 4096;  // LDS srcs staging per bucket (avg fill 2048)
constexpr int BHIST    = 256;   // blocks for hist/scatter passes

__device__ __forceinline__ float bf2f(ushort u) {
    return __uint_as_float((unsigned)u << 16);
}
__device__ __forceinline__ ushort f2bf(float f) {  // RTNE
    unsigned u = __float_as_uint(f);
    return (ushort)((u + 0x7FFF + ((u >> 16) & 1)) >> 16);
}

// ---- pass 1: per-block bucket histogram. ghist[b*B + blk] ----
__global__ __launch_bounds__(256) void k_hist(const int* __restrict__ dst,
                                              int* __restrict__ ghist,
                                              int E, int NB, int epb) {
    __shared__ int h[NB_MAX];
    const int t = threadIdx.x;
    for (int b = t; b < NB; b += 256) h[b] = 0;
    __syncthreads();
    const int e0 = blockIdx.x * epb;
    const int e1 = min(E, e0 + epb);
    for (int e = e0 + t; e < e1; e += 256) atomicAdd(&h[dst[e] >> NB_SHIFT], 1);
    __syncthreads();
    for (int b = t; b < NB; b += 256) ghist[b * gridDim.x + blockIdx.x] = h[b];
}

// ---- scan level 1 ----
template <int TPB>
__global__ void k_scanL1(const int* __restrict__ in, int* __restrict__ out,
                         int* __restrict__ bsum, int ntot) {
    __shared__ int s[TPB];
    const int t = threadIdx.x;
    const int g = blockIdx.x * TPB + t;
    int v = (g < ntot) ? in[g] : 0;
    s[t] = v;
    __syncthreads();
    #pragma unroll
    for (int d = 1; d < TPB; d <<= 1) {
        int x = (t >= d) ? s[t - d] : 0;
        __syncthreads();
        s[t] += x;
        __syncthreads();
    }
    if (g < ntot) out[g] = s[t] - v;
    if (t == TPB - 1) bsum[blockIdx.x] = s[t];
}

// ---- scan level 2: exclusive scan of <=512 block sums ----
__global__ void k_scanL2(int* __restrict__ bsum, int nb) {
    __shared__ int s[512];
    const int t = threadIdx.x;
    int v = (t < nb) ? bsum[t] : 0;
    s[t] = v;
    __syncthreads();
    #pragma unroll
    for (int d = 1; d < 512; d <<= 1) {
        int x = (t >= d) ? s[t - d] : 0;
        __syncthreads();
        s[t] += x;
        __syncthreads();
    }
    if (t < nb) bsum[t] = s[t] - v;
}

// ---- pass 2: scatter (src,dst) into bucket-grouped pairs ----
__global__ __launch_bounds__(256) void k_scatter(const int* __restrict__ src,
                                                 const int* __restrict__ dst,
                                                 const int* __restrict__ scan,
                                                 const int* __restrict__ bsum,
                                                 int2* __restrict__ pairs,
                                                 int E, int NB, int epb) {
    __shared__ int cur[NB_MAX];
    const int t = threadIdx.x;
    const int B = gridDim.x;
    const int blk = blockIdx.x;
    for (int b = t; b < NB; b += 256) {
        int idx = b * B + blk;
        cur[b] = scan[idx] + bsum[idx >> 9];
    }
    __syncthreads();
    const int e0 = blk * epb;
    const int e1 = min(E, e0 + epb);
    for (int e = e0 + t; e < e1; e += 256) {
        int d = dst[e];
        int slot = atomicAdd(&cur[d >> NB_SHIFT], 1);
        pairs[slot] = make_int2(src[e], d);
    }
}

// ---- pass 3: one block per bucket; local CSR in LDS, coalesced srcs out ----
__global__ __launch_bounds__(256) void k_build(const int2* __restrict__ pairs,
                                               const int* __restrict__ scan,
                                               const int* __restrict__ bsum,
                                               int* __restrict__ srcs,
                                               int* __restrict__ off,
                                               float* __restrict__ dinv,
                                               int n, int E, int NB, int B) {
    __shared__ int h[128], loff[128], curs[128];
    __shared__ int sb[BCAP];
    const int t = threadIdx.x;
    const int bk = blockIdx.x;
    const int i0 = bk * B;
    const int base = scan[i0] + bsum[i0 >> 9];
    const int nextbase = (bk + 1 < NB) ? (scan[i0 + B] + bsum[(i0 + B) >> 9]) : E;
    const int count = nextbase - base;
    if (t < 128) h[t] = 0;
    __syncthreads();
    for (int e = t; e < count; e += 256) atomicAdd(&h[pairs[base + e].y & 127], 1);
    __syncthreads();
    if (t < 128) loff[t] = h[t];
    __syncthreads();
    #pragma unroll
    for (int d = 1; d < 128; d <<= 1) {
        int x = 0;
        if (t < 128 && t >= d) x = loff[t - d];
        __syncthreads();
        if (t < 128) loff[t] += x;
        __syncthreads();
    }
    if (t < 128) curs[t] = loff[t] - h[t];  // exclusive
    __syncthreads();
    for (int e = t; e < count; e += 256) {
        int2 p = pairs[base + e];
        int slot = atomicAdd(&curs[p.y & 127], 1);
        if (slot < BCAP) sb[slot] = p.x;
        else srcs[base + slot] = p.x;  // overflow fallback (statistically unreachable)
    }
    __syncthreads();
    const int lim = min(count, BCAP);
    for (int e = t; e < lim; e += 256) srcs[base + e] = sb[e];
    const int node0 = bk << NB_SHIFT;
    if (t < 128) {
        int node = node0 + t;
        if (node < n) {
            off[node] = base + (loff[t] - h[t]);
            dinv[node] = rsqrtf((float)(h[t] + 1));
        }
    }
    if (bk == 0 && t == 0) off[n] = E;
}

// fp32 tiled GEMM, bf16 output: C[M,N] = A[M,K] @ B[K,N].
template <int K, int N, int BM, int BK, int TM, int TN>
__global__ __launch_bounds__(256) void k_gemm_bf16out(
    const float* __restrict__ A, const float* __restrict__ B,
    ushort* __restrict__ C, int M) {
    constexpr int BN = N;
    constexpr int NTX = BN / TN;
    __shared__ float As[BM][BK];
    __shared__ float Bs[BK][BN];
    const int t = threadIdx.x;
    const int tx = t % NTX;
    const int ty = t / NTX;
    const int row0 = blockIdx.x * BM;
    float acc[TM][TN] = {};
    for (int kc = 0; kc < K; kc += BK) {
        #pragma unroll
        for (int i = 0; i < BM * BK / (256 * 4); ++i) {
            int f = (t + i * 256) * 4;
            int r = f / BK, kq = f % BK;
            float4 v = make_float4(0.f, 0.f, 0.f, 0.f);
            if (row0 + r < M)
                v = *(const float4*)(A + (size_t)(row0 + r) * K + kc + kq);
            *(float4*)&As[r][kq] = v;
        }
        #pragma unroll
        for (int i = 0; i < BK * BN / (256 * 4); ++i) {
            int f = (t + i * 256) * 4;
            int r = f / BN, c = f % BN;
            *(float4*)&Bs[r][c] = *(const float4*)(B + (size_t)(kc + r) * N + c);
        }
        __syncthreads();
        #pragma unroll
        for (int kk = 0; kk < BK; ++kk) {
            float a[TM], b[TN];
            #pragma unroll
            for (int i = 0; i < TM; ++i) a[i] = As[ty * TM + i][kk];
            #pragma unroll
            for (int j = 0; j < TN; ++j) b[j] = Bs[kk][tx * TN + j];
            #pragma unroll
            for (int i = 0; i < TM; ++i)
                #pragma unroll
                for (int j = 0; j < TN; ++j)
                    acc[i][j] = fmaf(a[i], b[j], acc[i][j]);
        }
        __syncthreads();
    }
    #pragma unroll
    for (int i = 0; i < TM; ++i) {
        int r = row0 + ty * TM + i;
        if (r < M) {
            ushort4 o;
            o.x = f2bf(acc[i][0]);
            o.y = f2bf(acc[i][1]);
            o.z = f2bf(acc[i][2]);
            o.w = f2bf(acc[i][3]);
            *(ushort4*)(C + (size_t)r * N + tx * TN) = o;
        }
    }
}

// ---- FUSED agg1 + GEMM2, bf16 storage. One wave per node, 256-thr blocks.
// row = relu(agg(h1_bf16) + b1) in fp32 regs; stash in wave's LDS slot;
// h3_bf16[node][lane] = sum_k row[k] * bf2f(W2s[k][lane]).
// LDS = 16 KB W2s(bf16) + 2 KB stage -> 8 blocks/CU, 32 waves (full cap).
__global__ __launch_bounds__(256) void k_agg_mm(
    const ushort* __restrict__ h, const int* __restrict__ off,
    const int* __restrict__ srcs, const float* __restrict__ dinv,
    const float* __restrict__ b1, const float* __restrict__ W2,
    ushort* __restrict__ h3, int n) {
    __shared__ ushort W2s[128 * 64];
    __shared__ float2 stage[256];
    const int tid = threadIdx.x;
    // stage W2 as bf16: 8192 floats, 32 per thread
    #pragma unroll
    for (int i = 0; i < 8; ++i) {
        int f = (tid + i * 256) * 4;
        float4 v = *(const float4*)&W2[f];
        ushort4 o;
        o.x = f2bf(v.x); o.y = f2bf(v.y); o.z = f2bf(v.z); o.w = f2bf(v.w);
        *(ushort4*)&W2s[f] = o;
    }
    __syncthreads();  // only barrier; before any divergence
    const int lane = tid & 63;
    const int wbase = tid & ~63;
    const int wid = blockIdx.x * 4 + (tid >> 6);
    if (wid >= n) return;
    const float di = dinv[wid];
    const int e0 = off[wid], e1 = off[wid + 1];
    const ushort2* hp = (const ushort2*)h;  // 2 channels per lane
    ushort2 rs = hp[(size_t)wid * 64 + lane];
    float2 acc = make_float2(bf2f(rs.x) * di * di, bf2f(rs.y) * di * di);
    for (int e = e0; e < e1; e += 64) {
        int m = e1 - e;
        if (m > 64) m = 64;
        float2 pk = make_float2(0.f, 0.f);
        if (lane < m) {
            int s = srcs[e + lane];
            pk.x = __int_as_float(s);
            pk.y = dinv[s] * di;
        }
        stage[tid] = pk;
        #pragma unroll 4
        for (int j = 0; j < m; ++j) {
            float2 sw = stage[wbase + j];
            int sj = __float_as_int(sw.x);
            float wj = sw.y;
            ushort2 v = hp[(size_t)sj * 64 + lane];
            acc.x = fmaf(bf2f(v.x), wj, acc.x);
            acc.y = fmaf(bf2f(v.y), wj, acc.y);
        }
    }
    // bias + relu -> h2 row (fp32); stash in this wave's stage region
    float2 bb = ((const float2*)b1)[lane];
    acc.x = fmaxf(acc.x + bb.x, 0.f);
    acc.y = fmaxf(acc.y + bb.y, 0.f);
    stage[tid] = acc;  // flat: row[2*lane], row[2*lane+1]
    const float* row = (const float*)&stage[wbase];
    // lane computes channel c = lane. row[k]: wave-uniform broadcast;
    // W2s[k*64+lane] u16: 2 lanes/bank (free).
    float s0 = 0.f, s1 = 0.f, s2 = 0.f, s3 = 0.f;
    #pragma unroll 8
    for (int k = 0; k < 128; k += 4) {
        s0 = fmaf(row[k + 0], bf2f(W2s[(k + 0) * 64 + lane]), s0);
        s1 = fmaf(row[k + 1], bf2f(W2s[(k + 1) * 64 + lane]), s1);
        s2 = fmaf(row[k + 2], bf2f(W2s[(k + 2) * 64 + lane]), s2);
        s3 = fmaf(row[k + 3], bf2f(W2s[(k + 3) * 64 + lane]), s3);
    }
    h3[(size_t)wid * 64 + lane] = f2bf((s0 + s1) + (s2 + s3));
}

// pull aggregation (64-wide, bf16 input, fp32 out): out = agg(h3) + b2.
__global__ __launch_bounds__(256) void k_aggregate64(
    const ushort* __restrict__ h, const int* __restrict__ off,
    const int* __restrict__ srcs, const float* __restrict__ dinv,
    const float* __restrict__ bias, float* __restrict__ out, int n) {
    __shared__ float2 stage[256];
    const int tid = threadIdx.x;
    const int lane = tid & 63;
    const int wbase = tid & ~63;
    int wid = (int)((blockIdx.x * (size_t)blockDim.x + tid) >> 6);
    if (wid >= n) return;
    const float di = dinv[wid];
    const int e0 = off[wid], e1 = off[wid + 1];
    float acc = bf2f(h[(size_t)wid * 64 + lane]) * di * di;
    for (int e = e0; e < e1; e += 64) {
        int m = e1 - e;
        if (m > 64) m = 64;
        float2 pk = make_float2(0.f, 0.f);
        if (lane < m) {
            int s = srcs[e + lane];
            pk.x = __int_as_float(s);
            pk.y = dinv[s] * di;
        }
        stage[tid] = pk;
        #pragma unroll 4
        for (int j = 0; j < m; ++j) {
            float2 sw = stage[wbase + j];
            int sj = __float_as_int(sw.x);
            float wj = sw.y;
            acc = fmaf(bf2f(h[(size_t)sj * 64 + lane]), wj, acc);
        }
    }
    out[(size_t)wid * 64 + lane] = acc + bias[lane];
}

extern "C" void kernel_launch(void* const* d_in, const int* in_sizes, int n_in,
                              void* d_out, int out_size, void* d_ws, size_t ws_size,
                              hipStream_t stream) {
    const float* x  = (const float*)d_in[0];
    const int*   ei = (const int*)d_in[1];
    const float* W1 = (const float*)d_in[2];
    const float* b1 = (const float*)d_in[3];
    const float* W2 = (const float*)d_in[4];
    const float* b2 = (const float*)d_in[5];
    float* out = (float*)d_out;

    const int n = in_sizes[0] / 256;   // 100000
    const int E = in_sizes[1] / 2;     // 1600000
    const int* src = ei;
    const int* dst = ei + E;

    const int NB  = (n + 127) >> NB_SHIFT;           // 782 buckets
    const int B   = BHIST;                           // 256 hist/scatter blocks
    const int epb = (E + B - 1) / B;                 // edges per block
    const int ntot = NB * B;                         // scan length (200192)
    const int gL1 = (ntot + 511) / 512;              // 391 <= 512

    // workspace carve (256B aligned), ~60 MB. pairs aliases h1 (dead before gemm1).
    char* p = (char*)d_ws;
    auto alloc = [&](size_t bytes) {
        char* q = p;
        p += (bytes + 255) & ~(size_t)255;
        return q;
    };
    int*    ghist = (int*)alloc((size_t)ntot * 4);
    int*    scan  = (int*)alloc((size_t)ntot * 4);
    int*    bsum  = (int*)alloc(2048);
    int*    off   = (int*)alloc((size_t)(n + 1) * 4);
    float*  dinv  = (float*)alloc((size_t)n * 4);
    int*    srcs  = (int*)alloc((size_t)E * 4);
    ushort* h1    = (ushort*)alloc((size_t)n * 128 * 2);  // bf16, 25.6 MB
    ushort* h3    = (ushort*)alloc((size_t)n * 64 * 2);   // bf16, 12.8 MB
    int2*   pairs = (int2*)h1;  // E*8 = 12.8 MB <= h1's 25.6 MB; dead before gemm1

    // CSR build
    k_hist<<<B, 256, 0, stream>>>(dst, ghist, E, NB, epb);
    k_scanL1<512><<<gL1, 512, 0, stream>>>(ghist, scan, bsum, ntot);
    k_scanL2<<<1, 512, 0, stream>>>(bsum, gL1);
    k_scatter<<<B, 256, 0, stream>>>(src, dst, scan, bsum, pairs, E, NB, epb);
    k_build<<<NB, 256, 0, stream>>>(pairs, scan, bsum, srcs, off, dinv, n, E, NB, B);

    // layer 1 transform: h1 = bf16(x@W1)
    k_gemm_bf16out<256, 128, 64, 32, 8, 4><<<(n + 63) / 64, 256, 0, stream>>>(x, W1, h1, n);
    // fused: h3 = bf16( relu(agg(h1)+b1) @ W2 )
    k_agg_mm<<<(n + 3) / 4, 256, 0, stream>>>(h1, off, srcs, dinv, b1, W2, h3, n);
    // layer 2 aggregate: out = agg(h3) + b2  (fp32 out)
    k_aggregate64<<<(n + 3) / 4, 256, 0, stream>>>(h3, off, srcs, dinv, b2, out, n);
}

// Round 11
// 455.172 us; speedup vs baseline: 1.3721x; 1.0399x over previous
//
#include <hip/hip_runtime.h>

// 2-layer GCN (PyG GCNConv semantics). CSR via bucketed radix scatter (r5).
// r7: GEMM2 fused into agg1 epilogue. r9: bf16 storage for gathered tensors
// (FETCH 414->194 MB, confirmed). r10: gather is LATENCY-bound (ILP=4, ~500cy
// L3-class) -> static 8-wide load batches, zero-weight padding, no remainder.
//
// d_in: 0=x [n,256] f32, 1=edge_index [2,E] int32, 2=W1 [256,128], 3=b1 [128],
//       4=W2 [128,64], 5=b2 [64].  d_out: [n,64] f32.

constexpr int NB_SHIFT = 7;     // 128 nodes per bucket
constexpr int NB_MAX   = 1024;  // supports n <= 131072
constexpr int BCAP     = 4096;  // LDS srcs staging per bucket (avg fill 2048)
constexpr int BHIST    = 256;   // blocks for hist/scatter passes

__device__ __forceinline__ float bf2f(ushort u) {
    return __uint_as_float((unsigned)u << 16);
}
__device__ __forceinline__ ushort f2bf(float f) {  // RTNE
    unsigned u = __float_as_uint(f);
    return (ushort)((u + 0x7FFF + ((u >> 16) & 1)) >> 16);
}

// ---- pass 1: per-block bucket histogram. ghist[b*B + blk] ----
__global__ __launch_bounds__(256) void k_hist(const int* __restrict__ dst,
                                              int* __restrict__ ghist,
                                              int E, int NB, int epb) {
    __shared__ int h[NB_MAX];
    const int t = threadIdx.x;
    for (int b = t; b < NB; b += 256) h[b] = 0;
    __syncthreads();
    const int e0 = blockIdx.x * epb;
    const int e1 = min(E, e0 + epb);
    for (int e = e0 + t; e < e1; e += 256) atomicAdd(&h[dst[e] >> NB_SHIFT], 1);
    __syncthreads();
    for (int b = t; b < NB; b += 256) ghist[b * gridDim.x + blockIdx.x] = h[b];
}

// ---- scan level 1 ----
template <int TPB>
__global__ void k_scanL1(const int* __restrict__ in, int* __restrict__ out,
                         int* __restrict__ bsum, int ntot) {
    __shared__ int s[TPB];
    const int t = threadIdx.x;
    const int g = blockIdx.x * TPB + t;
    int v = (g < ntot) ? in[g] : 0;
    s[t] = v;
    __syncthreads();
    #pragma unroll
    for (int d = 1; d < TPB; d <<= 1) {
        int x = (t >= d) ? s[t - d] : 0;
        __syncthreads();
        s[t] += x;
        __syncthreads();
    }
    if (g < ntot) out[g] = s[t] - v;
    if (t == TPB - 1) bsum[blockIdx.x] = s[t];
}

// ---- scan level 2: exclusive scan of <=512 block sums ----
__global__ void k_scanL2(int* __restrict__ bsum, int nb) {
    __shared__ int s[512];
    const int t = threadIdx.x;
    int v = (t < nb) ? bsum[t] : 0;
    s[t] = v;
    __syncthreads();
    #pragma unroll
    for (int d = 1; d < 512; d <<= 1) {
        int x = (t >= d) ? s[t - d] : 0;
        __syncthreads();
        s[t] += x;
        __syncthreads();
    }
    if (t < nb) bsum[t] = s[t] - v;
}

// ---- pass 2: scatter (src,dst) into bucket-grouped pairs ----
__global__ __launch_bounds__(256) void k_scatter(const int* __restrict__ src,
                                                 const int* __restrict__ dst,
                                                 const int* __restrict__ scan,
                                                 const int* __restrict__ bsum,
                                                 int2* __restrict__ pairs,
                                                 int E, int NB, int epb) {
    __shared__ int cur[NB_MAX];
    const int t = threadIdx.x;
    const int B = gridDim.x;
    const int blk = blockIdx.x;
    for (int b = t; b < NB; b += 256) {
        int idx = b * B + blk;
        cur[b] = scan[idx] + bsum[idx >> 9];
    }
    __syncthreads();
    const int e0 = blk * epb;
    const int e1 = min(E, e0 + epb);
    for (int e = e0 + t; e < e1; e += 256) {
        int d = dst[e];
        int slot = atomicAdd(&cur[d >> NB_SHIFT], 1);
        pairs[slot] = make_int2(src[e], d);
    }
}

// ---- pass 3: one block per bucket; local CSR in LDS, coalesced srcs out ----
__global__ __launch_bounds__(256) void k_build(const int2* __restrict__ pairs,
                                               const int* __restrict__ scan,
                                               const int* __restrict__ bsum,
                                               int* __restrict__ srcs,
                                               int* __restrict__ off,
                                               float* __restrict__ dinv,
                                               int n, int E, int NB, int B) {
    __shared__ int h[128], loff[128], curs[128];
    __shared__ int sb[BCAP];
    const int t = threadIdx.x;
    const int bk = blockIdx.x;
    const int i0 = bk * B;
    const int base = scan[i0] + bsum[i0 >> 9];
    const int nextbase = (bk + 1 < NB) ? (scan[i0 + B] + bsum[(i0 + B) >> 9]) : E;
    const int count = nextbase - base;
    if (t < 128) h[t] = 0;
    __syncthreads();
    for (int e = t; e < count; e += 256) atomicAdd(&h[pairs[base + e].y & 127], 1);
    __syncthreads();
    if (t < 128) loff[t] = h[t];
    __syncthreads();
    #pragma unroll
    for (int d = 1; d < 128; d <<= 1) {
        int x = 0;
        if (t < 128 && t >= d) x = loff[t - d];
        __syncthreads();
        if (t < 128) loff[t] += x;
        __syncthreads();
    }
    if (t < 128) curs[t] = loff[t] - h[t];  // exclusive
    __syncthreads();
    for (int e = t; e < count; e += 256) {
        int2 p = pairs[base + e];
        int slot = atomicAdd(&curs[p.y & 127], 1);
        if (slot < BCAP) sb[slot] = p.x;
        else srcs[base + slot] = p.x;  // overflow fallback (statistically unreachable)
    }
    __syncthreads();
    const int lim = min(count, BCAP);
    for (int e = t; e < lim; e += 256) srcs[base + e] = sb[e];
    const int node0 = bk << NB_SHIFT;
    if (t < 128) {
        int node = node0 + t;
        if (node < n) {
            off[node] = base + (loff[t] - h[t]);
            dinv[node] = rsqrtf((float)(h[t] + 1));
        }
    }
    if (bk == 0 && t == 0) off[n] = E;
}

// fp32 tiled GEMM, bf16 output: C[M,N] = A[M,K] @ B[K,N].
template <int K, int N, int BM, int BK, int TM, int TN>
__global__ __launch_bounds__(256) void k_gemm_bf16out(
    const float* __restrict__ A, const float* __restrict__ B,
    ushort* __restrict__ C, int M) {
    constexpr int BN = N;
    constexpr int NTX = BN / TN;
    __shared__ float As[BM][BK];
    __shared__ float Bs[BK][BN];
    const int t = threadIdx.x;
    const int tx = t % NTX;
    const int ty = t / NTX;
    const int row0 = blockIdx.x * BM;
    float acc[TM][TN] = {};
    for (int kc = 0; kc < K; kc += BK) {
        #pragma unroll
        for (int i = 0; i < BM * BK / (256 * 4); ++i) {
            int f = (t + i * 256) * 4;
            int r = f / BK, kq = f % BK;
            float4 v = make_float4(0.f, 0.f, 0.f, 0.f);
            if (row0 + r < M)
                v = *(const float4*)(A + (size_t)(row0 + r) * K + kc + kq);
            *(float4*)&As[r][kq] = v;
        }
        #pragma unroll
        for (int i = 0; i < BK * BN / (256 * 4); ++i) {
            int f = (t + i * 256) * 4;
            int r = f / BN, c = f % BN;
            *(float4*)&Bs[r][c] = *(const float4*)(B + (size_t)(kc + r) * N + c);
        }
        __syncthreads();
        #pragma unroll
        for (int kk = 0; kk < BK; ++kk) {
            float a[TM], b[TN];
            #pragma unroll
            for (int i = 0; i < TM; ++i) a[i] = As[ty * TM + i][kk];
            #pragma unroll
            for (int j = 0; j < TN; ++j) b[j] = Bs[kk][tx * TN + j];
            #pragma unroll
            for (int i = 0; i < TM; ++i)
                #pragma unroll
                for (int j = 0; j < TN; ++j)
                    acc[i][j] = fmaf(a[i], b[j], acc[i][j]);
        }
        __syncthreads();
    }
    #pragma unroll
    for (int i = 0; i < TM; ++i) {
        int r = row0 + ty * TM + i;
        if (r < M) {
            ushort4 o;
            o.x = f2bf(acc[i][0]);
            o.y = f2bf(acc[i][1]);
            o.z = f2bf(acc[i][2]);
            o.w = f2bf(acc[i][3]);
            *(ushort4*)(C + (size_t)r * N + tx * TN) = o;
        }
    }
}

// ---- FUSED agg1 + GEMM2, bf16 storage, 8-deep gather pipeline.
// Chunk padded to multiple of 8 with zero-weight entries (stage slots for
// lane>=m hold (0,0): row-0 load x 0.0 -> harmless, stays L1-hot). All batch
// arrays statically indexed (runtime-indexed ext arrays -> scratch).
__global__ __launch_bounds__(256) void k_agg_mm(
    const ushort* __restrict__ h, const int* __restrict__ off,
    const int* __restrict__ srcs, const float* __restrict__ dinv,
    const float* __restrict__ b1, const float* __restrict__ W2,
    ushort* __restrict__ h3, int n) {
    __shared__ ushort W2s[128 * 64];
    __shared__ float2 stage[256];
    const int tid = threadIdx.x;
    #pragma unroll
    for (int i = 0; i < 8; ++i) {
        int f = (tid + i * 256) * 4;
        float4 v = *(const float4*)&W2[f];
        ushort4 o;
        o.x = f2bf(v.x); o.y = f2bf(v.y); o.z = f2bf(v.z); o.w = f2bf(v.w);
        *(ushort4*)&W2s[f] = o;
    }
    __syncthreads();  // only barrier; before any divergence
    const int lane = tid & 63;
    const int wbase = tid & ~63;
    const int wid = blockIdx.x * 4 + (tid >> 6);
    if (wid >= n) return;
    const float di = dinv[wid];
    const int e0 = off[wid], e1 = off[wid + 1];
    const ushort2* hp = (const ushort2*)h + lane;  // per-lane base
    ushort2 rs = hp[(size_t)wid * 64];
    float2 acc = make_float2(bf2f(rs.x) * di * di, bf2f(rs.y) * di * di);
    for (int e = e0; e < e1; e += 64) {
        int m = e1 - e;
        if (m > 64) m = 64;
        float2 pk = make_float2(0.f, 0.f);
        if (lane < m) {
            int s = srcs[e + lane];
            pk.x = __int_as_float(s);
            pk.y = dinv[s] * di;
        }
        stage[tid] = pk;
        const int R = (m + 7) & ~7;
        for (int j = 0; j < R; j += 8) {
            int a[8]; float w[8]; ushort2 v[8];
            #pragma unroll
            for (int k = 0; k < 8; ++k) {
                float2 sw = stage[wbase + j + k];
                a[k] = __float_as_int(sw.x);
                w[k] = sw.y;
            }
            #pragma unroll
            for (int k = 0; k < 8; ++k) v[k] = hp[(size_t)a[k] * 64];
            #pragma unroll
            for (int k = 0; k < 8; ++k) {
                acc.x = fmaf(bf2f(v[k].x), w[k], acc.x);
                acc.y = fmaf(bf2f(v[k].y), w[k], acc.y);
            }
        }
    }
    // bias + relu -> h2 row (fp32); stash in this wave's stage region
    float2 bb = ((const float2*)b1)[lane];
    acc.x = fmaxf(acc.x + bb.x, 0.f);
    acc.y = fmaxf(acc.y + bb.y, 0.f);
    stage[tid] = acc;  // flat: row[2*lane], row[2*lane+1]
    const float* row = (const float*)&stage[wbase];
    float s0 = 0.f, s1 = 0.f, s2 = 0.f, s3 = 0.f;
    #pragma unroll 8
    for (int k = 0; k < 128; k += 4) {
        s0 = fmaf(row[k + 0], bf2f(W2s[(k + 0) * 64 + lane]), s0);
        s1 = fmaf(row[k + 1], bf2f(W2s[(k + 1) * 64 + lane]), s1);
        s2 = fmaf(row[k + 2], bf2f(W2s[(k + 2) * 64 + lane]), s2);
        s3 = fmaf(row[k + 3], bf2f(W2s[(k + 3) * 64 + lane]), s3);
    }
    h3[(size_t)wid * 64 + lane] = f2bf((s0 + s1) + (s2 + s3));
}

// pull aggregation (64-wide, bf16 input, fp32 out), 8-deep gather pipeline.
__global__ __launch_bounds__(256) void k_aggregate64(
    const ushort* __restrict__ h, const int* __restrict__ off,
    const int* __restrict__ srcs, const float* __restrict__ dinv,
    const float* __restrict__ bias, float* __restrict__ out, int n) {
    __shared__ float2 stage[256];
    const int tid = threadIdx.x;
    const int lane = tid & 63;
    const int wbase = tid & ~63;
    int wid = (int)((blockIdx.x * (size_t)blockDim.x + tid) >> 6);
    if (wid >= n) return;
    const float di = dinv[wid];
    const int e0 = off[wid], e1 = off[wid + 1];
    const ushort* hl = h + lane;  // per-lane base
    float acc = bf2f(hl[(size_t)wid * 64]) * di * di;
    for (int e = e0; e < e1; e += 64) {
        int m = e1 - e;
        if (m > 64) m = 64;
        float2 pk = make_float2(0.f, 0.f);
        if (lane < m) {
            int s = srcs[e + lane];
            pk.x = __int_as_float(s);
            pk.y = dinv[s] * di;
        }
        stage[tid] = pk;
        const int R = (m + 7) & ~7;
        for (int j = 0; j < R; j += 8) {
            int a[8]; float w[8]; ushort v[8];
            #pragma unroll
            for (int k = 0; k < 8; ++k) {
                float2 sw = stage[wbase + j + k];
                a[k] = __float_as_int(sw.x);
                w[k] = sw.y;
            }
            #pragma unroll
            for (int k = 0; k < 8; ++k) v[k] = hl[(size_t)a[k] * 64];
            #pragma unroll
            for (int k = 0; k < 8; ++k) acc = fmaf(bf2f(v[k]), w[k], acc);
        }
    }
    out[(size_t)wid * 64 + lane] = acc + bias[lane];
}

extern "C" void kernel_launch(void* const* d_in, const int* in_sizes, int n_in,
                              void* d_out, int out_size, void* d_ws, size_t ws_size,
                              hipStream_t stream) {
    const float* x  = (const float*)d_in[0];
    const int*   ei = (const int*)d_in[1];
    const float* W1 = (const float*)d_in[2];
    const float* b1 = (const float*)d_in[3];
    const float* W2 = (const float*)d_in[4];
    const float* b2 = (const float*)d_in[5];
    float* out = (float*)d_out;

    const int n = in_sizes[0] / 256;   // 100000
    const int E = in_sizes[1] / 2;     // 1600000
    const int* src = ei;
    const int* dst = ei + E;

    const int NB  = (n + 127) >> NB_SHIFT;           // 782 buckets
    const int B   = BHIST;                           // 256 hist/scatter blocks
    const int epb = (E + B - 1) / B;                 // edges per block
    const int ntot = NB * B;                         // scan length (200192)
    const int gL1 = (ntot + 511) / 512;              // 391 <= 512

    // workspace carve (256B aligned), ~60 MB. pairs aliases h1 (dead before gemm1).
    char* p = (char*)d_ws;
    auto alloc = [&](size_t bytes) {
        char* q = p;
        p += (bytes + 255) & ~(size_t)255;
        return q;
    };
    int*    ghist = (int*)alloc((size_t)ntot * 4);
    int*    scan  = (int*)alloc((size_t)ntot * 4);
    int*    bsum  = (int*)alloc(2048);
    int*    off   = (int*)alloc((size_t)(n + 1) * 4);
    float*  dinv  = (float*)alloc((size_t)n * 4);
    int*    srcs  = (int*)alloc((size_t)E * 4);
    ushort* h1    = (ushort*)alloc((size_t)n * 128 * 2);  // bf16, 25.6 MB
    ushort* h3    = (ushort*)alloc((size_t)n * 64 * 2);   // bf16, 12.8 MB
    int2*   pairs = (int2*)h1;  // E*8 = 12.8 MB <= h1's 25.6 MB; dead before gemm1

    // CSR build
    k_hist<<<B, 256, 0, stream>>>(dst, ghist, E, NB, epb);
    k_scanL1<512><<<gL1, 512, 0, stream>>>(ghist, scan, bsum, ntot);
    k_scanL2<<<1, 512, 0, stream>>>(bsum, gL1);
    k_scatter<<<B, 256, 0, stream>>>(src, dst, scan, bsum, pairs, E, NB, epb);
    k_build<<<NB, 256, 0, stream>>>(pairs, scan, bsum, srcs, off, dinv, n, E, NB, B);

    // layer 1 transform: h1 = bf16(x@W1)
    k_gemm_bf16out<256, 128, 64, 32, 8, 4><<<(n + 63) / 64, 256, 0, stream>>>(x, W1, h1, n);
    // fused: h3 = bf16( relu(agg(h1)+b1) @ W2 )
    k_agg_mm<<<(n + 3) / 4, 256, 0, stream>>>(h1, off, srcs, dinv, b1, W2, h3, n);
    // layer 2 aggregate: out = agg(h3) + b2  (fp32 out)
    k_aggregate64<<<(n + 3) / 4, 256, 0, stream>>>(h3, off, srcs, dinv, b2, out, n);
}

// Round 14
// 450.488 us; speedup vs baseline: 1.3863x; 1.0104x over previous
//
#include <hip/hip_runtime.h>

// 2-layer GCN (PyG GCNConv semantics). CSR via bucketed radix scatter (r5).
// r7: GEMM2 fused into agg1 epilogue. r9: bf16 storage (FETCH 414->194 MB).
// r11 post-mortem: aggs are request-rate bound (byte-halving + ILP both ~null).
// r12: (a) gemm1 -> MFMA bf16 (was ~120us fp32 vector, ~35% of 157TF);
//      (b) precompute sw[e]=(src,dinv[src]) -> kills per-edge divergent gather.
//
// d_in: 0=x [n,256] f32, 1=edge_index [2,E] int32, 2=W1 [256,128], 3=b1 [128],
//       4=W2 [128,64], 5=b2 [64].  d_out: [n,64] f32.

constexpr int NB_SHIFT = 7;     // 128 nodes per bucket
constexpr int NB_MAX   = 1024;  // supports n <= 131072
constexpr int BCAP     = 4096;  // LDS srcs staging per bucket (avg fill 2048)
constexpr int BHIST    = 256;   // blocks for hist/scatter passes

typedef __attribute__((ext_vector_type(8))) short bf16x8;
typedef __attribute__((ext_vector_type(4))) float f32x4;

__device__ __forceinline__ float bf2f(ushort u) {
    return __uint_as_float((unsigned)u << 16);
}
__device__ __forceinline__ ushort f2bf(float f) {  // RTNE
    unsigned u = __float_as_uint(f);
    return (ushort)((u + 0x7FFF + ((u >> 16) & 1)) >> 16);
}

// ---- pass 1: per-block bucket histogram. ghist[b*B + blk] ----
__global__ __launch_bounds__(256) void k_hist(const int* __restrict__ dst,
                                              int* __restrict__ ghist,
                                              int E, int NB, int epb) {
    __shared__ int h[NB_MAX];
    const int t = threadIdx.x;
    for (int b = t; b < NB; b += 256) h[b] = 0;
    __syncthreads();
    const int e0 = blockIdx.x * epb;
    const int e1 = min(E, e0 + epb);
    for (int e = e0 + t; e < e1; e += 256) atomicAdd(&h[dst[e] >> NB_SHIFT], 1);
    __syncthreads();
    for (int b = t; b < NB; b += 256) ghist[b * gridDim.x + blockIdx.x] = h[b];
}

// ---- scan level 1 ----
template <int TPB>
__global__ void k_scanL1(const int* __restrict__ in, int* __restrict__ out,
                         int* __restrict__ bsum, int ntot) {
    __shared__ int s[TPB];
    const int t = threadIdx.x;
    const int g = blockIdx.x * TPB + t;
    int v = (g < ntot) ? in[g] : 0;
    s[t] = v;
    __syncthreads();
    #pragma unroll
    for (int d = 1; d < TPB; d <<= 1) {
        int x = (t >= d) ? s[t - d] : 0;
        __syncthreads();
        s[t] += x;
        __syncthreads();
    }
    if (g < ntot) out[g] = s[t] - v;
    if (t == TPB - 1) bsum[blockIdx.x] = s[t];
}

// ---- scan level 2: exclusive scan of <=512 block sums ----
__global__ void k_scanL2(int* __restrict__ bsum, int nb) {
    __shared__ int s[512];
    const int t = threadIdx.x;
    int v = (t < nb) ? bsum[t] : 0;
    s[t] = v;
    __syncthreads();
    #pragma unroll
    for (int d = 1; d < 512; d <<= 1) {
        int x = (t >= d) ? s[t - d] : 0;
        __syncthreads();
        s[t] += x;
        __syncthreads();
    }
    if (t < nb) bsum[t] = s[t] - v;
}

// ---- pass 2: scatter (src,dst) into bucket-grouped pairs ----
__global__ __launch_bounds__(256) void k_scatter(const int* __restrict__ src,
                                                 const int* __restrict__ dst,
                                                 const int* __restrict__ scan,
                                                 const int* __restrict__ bsum,
                                                 int2* __restrict__ pairs,
                                                 int E, int NB, int epb) {
    __shared__ int cur[NB_MAX];
    const int t = threadIdx.x;
    const int B = gridDim.x;
    const int blk = blockIdx.x;
    for (int b = t; b < NB; b += 256) {
        int idx = b * B + blk;
        cur[b] = scan[idx] + bsum[idx >> 9];
    }
    __syncthreads();
    const int e0 = blk * epb;
    const int e1 = min(E, e0 + epb);
    for (int e = e0 + t; e < e1; e += 256) {
        int d = dst[e];
        int slot = atomicAdd(&cur[d >> NB_SHIFT], 1);
        pairs[slot] = make_int2(src[e], d);
    }
}

// ---- pass 3: one block per bucket; local CSR in LDS, coalesced srcs out ----
__global__ __launch_bounds__(256) void k_build(const int2* __restrict__ pairs,
                                               const int* __restrict__ scan,
                                               const int* __restrict__ bsum,
                                               int* __restrict__ srcs,
                                               int* __restrict__ off,
                                               float* __restrict__ dinv,
                                               int n, int E, int NB, int B) {
    __shared__ int h[128], loff[128], curs[128];
    __shared__ int sb[BCAP];
    const int t = threadIdx.x;
    const int bk = blockIdx.x;
    const int i0 = bk * B;
    const int base = scan[i0] + bsum[i0 >> 9];
    const int nextbase = (bk + 1 < NB) ? (scan[i0 + B] + bsum[(i0 + B) >> 9]) : E;
    const int count = nextbase - base;
    if (t < 128) h[t] = 0;
    __syncthreads();
    for (int e = t; e < count; e += 256) atomicAdd(&h[pairs[base + e].y & 127], 1);
    __syncthreads();
    if (t < 128) loff[t] = h[t];
    __syncthreads();
    #pragma unroll
    for (int d = 1; d < 128; d <<= 1) {
        int x = 0;
        if (t < 128 && t >= d) x = loff[t - d];
        __syncthreads();
        if (t < 128) loff[t] += x;
        __syncthreads();
    }
    if (t < 128) curs[t] = loff[t] - h[t];  // exclusive
    __syncthreads();
    for (int e = t; e < count; e += 256) {
        int2 p = pairs[base + e];
        int slot = atomicAdd(&curs[p.y & 127], 1);
        if (slot < BCAP) sb[slot] = p.x;
        else srcs[base + slot] = p.x;  // overflow fallback (statistically unreachable)
    }
    __syncthreads();
    const int lim = min(count, BCAP);
    for (int e = t; e < lim; e += 256) srcs[base + e] = sb[e];
    const int node0 = bk << NB_SHIFT;
    if (t < 128) {
        int node = node0 + t;
        if (node < n) {
            off[node] = base + (loff[t] - h[t]);
            dinv[node] = rsqrtf((float)(h[t] + 1));
        }
    }
    if (bk == 0 && t == 0) off[n] = E;
}

// ---- sw[e] = (src bits, dinv[src]) : one divergent gather HERE instead of
//      one per edge in EACH agg kernel ----
__global__ __launch_bounds__(256) void k_wfill(const int* __restrict__ srcs,
                                               const float* __restrict__ dinv,
                                               float2* __restrict__ sw, int E) {
    int e = blockIdx.x * 256 + threadIdx.x;
    if (e < E) {
        int s = srcs[e];
        sw[e] = make_float2(__int_as_float(s), dinv[s]);
    }
}

// ---- MFMA bf16 GEMM1: h1 = bf16(x @ W1). 256 thr = 4 waves; BM=64, BN=128,
// BK=32. Wave w owns 16-row m-strip x 128 cols (8 n-tiles, 16x16x32 mfma).
// A/B frag: lane l -> row/col = l&15, k = (l>>4)*8+j (contiguous 16B/lane).
// C/D: row=(l>>4)*4+q, col=l&15 [m89 verified].
__global__ __launch_bounds__(256) void k_gemm_mfma(
    const float* __restrict__ A, const float* __restrict__ W,
    ushort* __restrict__ C, int M) {
    __shared__ ushort As[64][32];    // 4 KB
    __shared__ ushort Bs[128][40];   // transposed W tile, pad 32->40 (16B-aligned rows)
    const int t = threadIdx.x;
    const int w = t >> 6;
    const int l = t & 63;
    const int row0 = blockIdx.x * 64;
    f32x4 acc[8] = {};
    for (int kc = 0; kc < 256; kc += 32) {
        // stage A (64x32 f32 -> bf16), 8 elems/thread, coalesced rows of 32
        #pragma unroll
        for (int i = 0; i < 8; ++i) {
            int f = t + i * 256;
            int r = f >> 5, c = f & 31;
            float v = 0.f;
            if (row0 + r < M) v = A[(size_t)(row0 + r) * 256 + kc + c];
            As[r][c] = f2bf(v);
        }
        // stage W transposed: Bs[c][k] = W[kc+k][c]; t -> col c, k-pair block
        {
            int c = t & 127;
            int rr = t >> 7;  // 0/1
            #pragma unroll
            for (int i = 0; i < 8; ++i) {
                int k0 = (rr * 8 + i) * 2;
                ushort2 o;
                o.x = f2bf(W[(size_t)(kc + k0) * 128 + c]);
                o.y = f2bf(W[(size_t)(kc + k0 + 1) * 128 + c]);
                *(ushort2*)&Bs[c][k0] = o;
            }
        }
        __syncthreads();
        const int kg = l >> 4;   // k-group 0..3
        const int lr = l & 15;
        bf16x8 af = *(const bf16x8*)&As[w * 16 + lr][kg * 8];
        #pragma unroll
        for (int nt = 0; nt < 8; ++nt) {
            bf16x8 bf = *(const bf16x8*)&Bs[nt * 16 + lr][kg * 8];
            acc[nt] = __builtin_amdgcn_mfma_f32_16x16x32_bf16(af, bf, acc[nt], 0, 0, 0);
        }
        __syncthreads();
    }
    const int mrow = (l >> 4) * 4;
    const int col0 = l & 15;
    #pragma unroll
    for (int q = 0; q < 4; ++q) {
        int r = row0 + w * 16 + mrow + q;
        if (r < M) {
            #pragma unroll
            for (int nt = 0; nt < 8; ++nt)
                C[(size_t)r * 128 + nt * 16 + col0] = f2bf(acc[nt][q]);
        }
    }
}

// ---- FUSED agg1 + GEMM2, bf16 storage, 8-deep gather batches, packed sw ----
__global__ __launch_bounds__(256) void k_agg_mm(
    const ushort* __restrict__ h, const int* __restrict__ off,
    const float2* __restrict__ sw, const float* __restrict__ dinv,
    const float* __restrict__ b1, const float* __restrict__ W2,
    ushort* __restrict__ h3, int n) {
    __shared__ ushort W2s[128 * 64];
    __shared__ float2 stage[256];
    const int tid = threadIdx.x;
    #pragma unroll
    for (int i = 0; i < 8; ++i) {
        int f = (tid + i * 256) * 4;
        float4 v = *(const float4*)&W2[f];
        ushort4 o;
        o.x = f2bf(v.x); o.y = f2bf(v.y); o.z = f2bf(v.z); o.w = f2bf(v.w);
        *(ushort4*)&W2s[f] = o;
    }
    __syncthreads();  // only barrier; before any divergence
    const int lane = tid & 63;
    const int wbase = tid & ~63;
    const int wid = blockIdx.x * 4 + (tid >> 6);
    if (wid >= n) return;
    const float di = dinv[wid];
    const int e0 = off[wid], e1 = off[wid + 1];
    const ushort2* hp = (const ushort2*)h + lane;  // per-lane base
    ushort2 rs = hp[(size_t)wid * 64];
    float2 acc = make_float2(bf2f(rs.x) * di * di, bf2f(rs.y) * di * di);
    for (int e = e0; e < e1; e += 64) {
        int m = e1 - e;
        if (m > 64) m = 64;
        float2 pk = make_float2(0.f, 0.f);
        if (lane < m) {
            float2 s = sw[e + lane];   // coalesced 8B: (src bits, dinv[src])
            pk.x = s.x;
            pk.y = s.y * di;
        }
        stage[tid] = pk;
        const int R = (m + 7) & ~7;
        for (int j = 0; j < R; j += 8) {
            int a[8]; float w[8]; ushort2 v[8];
            #pragma unroll
            for (int k = 0; k < 8; ++k) {
                float2 swv = stage[wbase + j + k];
                a[k] = __float_as_int(swv.x);
                w[k] = swv.y;
            }
            #pragma unroll
            for (int k = 0; k < 8; ++k) v[k] = hp[(size_t)a[k] * 64];
            #pragma unroll
            for (int k = 0; k < 8; ++k) {
                acc.x = fmaf(bf2f(v[k].x), w[k], acc.x);
                acc.y = fmaf(bf2f(v[k].y), w[k], acc.y);
            }
        }
    }
    float2 bb = ((const float2*)b1)[lane];
    acc.x = fmaxf(acc.x + bb.x, 0.f);
    acc.y = fmaxf(acc.y + bb.y, 0.f);
    stage[tid] = acc;  // flat: row[2*lane], row[2*lane+1]
    const float* row = (const float*)&stage[wbase];
    float s0 = 0.f, s1 = 0.f, s2 = 0.f, s3 = 0.f;
    #pragma unroll 8
    for (int k = 0; k < 128; k += 4) {
        s0 = fmaf(row[k + 0], bf2f(W2s[(k + 0) * 64 + lane]), s0);
        s1 = fmaf(row[k + 1], bf2f(W2s[(k + 1) * 64 + lane]), s1);
        s2 = fmaf(row[k + 2], bf2f(W2s[(k + 2) * 64 + lane]), s2);
        s3 = fmaf(row[k + 3], bf2f(W2s[(k + 3) * 64 + lane]), s3);
    }
    h3[(size_t)wid * 64 + lane] = f2bf((s0 + s1) + (s2 + s3));
}

// ---- pull aggregation (64-wide, bf16 in, fp32 out), 8-deep, packed sw ----
__global__ __launch_bounds__(256) void k_aggregate64(
    const ushort* __restrict__ h, const int* __restrict__ off,
    const float2* __restrict__ sw, const float* __restrict__ dinv,
    const float* __restrict__ bias, float* __restrict__ out, int n) {
    __shared__ float2 stage[256];
    const int tid = threadIdx.x;
    const int lane = tid & 63;
    const int wbase = tid & ~63;
    int wid = (int)((blockIdx.x * (size_t)blockDim.x + tid) >> 6);
    if (wid >= n) return;
    const float di = dinv[wid];
    const int e0 = off[wid], e1 = off[wid + 1];
    const ushort* hl = h + lane;  // per-lane base
    float acc = bf2f(hl[(size_t)wid * 64]) * di * di;
    for (int e = e0; e < e1; e += 64) {
        int m = e1 - e;
        if (m > 64) m = 64;
        float2 pk = make_float2(0.f, 0.f);
        if (lane < m) {
            float2 s = sw[e + lane];
            pk.x = s.x;
            pk.y = s.y * di;
        }
        stage[tid] = pk;
        const int R = (m + 7) & ~7;
        for (int j = 0; j < R; j += 8) {
            int a[8]; float w[8]; ushort v[8];
            #pragma unroll
            for (int k = 0; k < 8; ++k) {
                float2 swv = stage[wbase + j + k];
                a[k] = __float_as_int(swv.x);
                w[k] = swv.y;
            }
            #pragma unroll
            for (int k = 0; k < 8; ++k) v[k] = hl[(size_t)a[k] * 64];
            #pragma unroll
            for (int k = 0; k < 8; ++k) acc = fmaf(bf2f(v[k]), w[k], acc);
        }
    }
    out[(size_t)wid * 64 + lane] = acc + bias[lane];
}

extern "C" void kernel_launch(void* const* d_in, const int* in_sizes, int n_in,
                              void* d_out, int out_size, void* d_ws, size_t ws_size,
                              hipStream_t stream) {
    const float* x  = (const float*)d_in[0];
    const int*   ei = (const int*)d_in[1];
    const float* W1 = (const float*)d_in[2];
    const float* b1 = (const float*)d_in[3];
    const float* W2 = (const float*)d_in[4];
    const float* b2 = (const float*)d_in[5];
    float* out = (float*)d_out;

    const int n = in_sizes[0] / 256;   // 100000
    const int E = in_sizes[1] / 2;     // 1600000
    const int* src = ei;
    const int* dst = ei + E;

    const int NB  = (n + 127) >> NB_SHIFT;           // 782 buckets
    const int B   = BHIST;                           // 256 hist/scatter blocks
    const int epb = (E + B - 1) / B;                 // edges per block
    const int ntot = NB * B;                         // scan length (200192)
    const int gL1 = (ntot + 511) / 512;              // 391 <= 512

    // workspace carve (256B aligned), ~75 MB. pairs aliases h1 (dead before gemm1).
    char* p = (char*)d_ws;
    auto alloc = [&](size_t bytes) {
        char* q = p;
        p += (bytes + 255) & ~(size_t)255;
        return q;
    };
    int*    ghist = (int*)alloc((size_t)ntot * 4);
    int*    scan  = (int*)alloc((size_t)ntot * 4);
    int*    bsum  = (int*)alloc(2048);
    int*    off   = (int*)alloc((size_t)(n + 1) * 4);
    float*  dinv  = (float*)alloc((size_t)n * 4);
    int*    srcs  = (int*)alloc((size_t)E * 4);
    float2* sw    = (float2*)alloc((size_t)E * 8);        // 12.8 MB
    ushort* h1    = (ushort*)alloc((size_t)n * 128 * 2);  // bf16, 25.6 MB
    ushort* h3    = (ushort*)alloc((size_t)n * 64 * 2);   // bf16, 12.8 MB
    int2*   pairs = (int2*)h1;  // E*8 = 12.8 MB <= h1's 25.6 MB; dead before gemm1

    // CSR build
    k_hist<<<B, 256, 0, stream>>>(dst, ghist, E, NB, epb);
    k_scanL1<512><<<gL1, 512, 0, stream>>>(ghist, scan, bsum, ntot);
    k_scanL2<<<1, 512, 0, stream>>>(bsum, gL1);
    k_scatter<<<B, 256, 0, stream>>>(src, dst, scan, bsum, pairs, E, NB, epb);
    k_build<<<NB, 256, 0, stream>>>(pairs, scan, bsum, srcs, off, dinv, n, E, NB, B);
    k_wfill<<<(E + 255) / 256, 256, 0, stream>>>(srcs, dinv, sw, E);

    // layer 1 transform: h1 = bf16(x@W1) via MFMA
    k_gemm_mfma<<<(n + 63) / 64, 256, 0, stream>>>(x, W1, h1, n);
    // fused: h3 = bf16( relu(agg(h1)+b1) @ W2 )
    k_agg_mm<<<(n + 3) / 4, 256, 0, stream>>>(h1, off, sw, dinv, b1, W2, h3, n);
    // layer 2 aggregate: out = agg(h3) + b2  (fp32 out)
    k_aggregate64<<<(n + 3) / 4, 256, 0, stream>>>(h3, off, sw, dinv, b2, out, n);
}